// Round 7
// baseline (277.232 us; speedup 1.0000x reference)
//
#include <hip/hip_runtime.h>
#include <hip/hip_bf16.h>
#include <math.h>

#define TT 8192
#define DD 512
#define HH 1024
#define EE 16
#define NSLOT 18432   // 144 * 128 max padded slots
#define MAXTILES 144
#define BM 128
#define RETRYCAP 1024

typedef __attribute__((ext_vector_type(8))) short bf16x8;
typedef __attribute__((ext_vector_type(4))) float f32x4;

__device__ __forceinline__ unsigned short f2bf(float f) {
  union { float f; unsigned u; } v; v.f = f;
  unsigned r = v.u + 0x7fffu + ((v.u >> 16) & 1u);
  return (unsigned short)(r >> 16);
}

__device__ __forceinline__ float bf2f(unsigned short u) {
  union { unsigned u; float f; } v; v.u = ((unsigned)u) << 16;
  return v.f;
}

__device__ __forceinline__ void gload16(const void* g, void* l) {
  __builtin_amdgcn_global_load_lds(
      (const __attribute__((address_space(1))) unsigned int*)g,
      (__attribute__((address_space(3))) unsigned int*)l, 16, 0, 0);
}

// Abramowitz-Stegun 7.1.26 erf approx (|err| <= 1.5e-7), ~12 VALU ops
__device__ __forceinline__ float gelu_f(float v) {
  float s = fabsf(v) * 0.70710678118654752f;
  float t = 1.0f / (1.0f + 0.3275911f * s);
  float poly = t * (0.254829592f +
              t * (-0.284496736f +
              t * (1.421413741f +
              t * (-1.453152027f +
              t * 1.061405429f))));
  float erfa = 1.0f - poly * __expf(-s * s);
  float erfv = (v >= 0.f) ? erfa : -erfa;
  return 0.5f * v * (1.0f + erfv);
}

// ---------------- prep: transposeW1 | transposeW2 | gatecv in one launch ----
struct GateSm { float wg[DD][EE]; float xs[8][520]; };
union PrepSm {
  unsigned short t[64][68];
  GateSm g;
};

__device__ __forceinline__ void transpose_body(
    const float* __restrict__ src, unsigned short* __restrict__ dst,
    int R, int C, int c0, int r0, unsigned short (*t)[68], int tid) {
#pragma unroll
  for (int p = 0; p < 4; p++) {
    int r = tid >> 2;
    int c4 = (tid & 3) + p * 4;
    float4 v = *(const float4*)(src + (size_t)(r0 + r) * C + c0 + c4 * 4);
    t[c4 * 4 + 0][r] = f2bf(v.x);
    t[c4 * 4 + 1][r] = f2bf(v.y);
    t[c4 * 4 + 2][r] = f2bf(v.z);
    t[c4 * 4 + 3][r] = f2bf(v.w);
  }
  __syncthreads();
#pragma unroll
  for (int p = 0; p < 4; p++) {
    int oc = (tid >> 4) + p * 16;
    int ch = tid & 15;
    ushort4 v = *(ushort4*)(&t[oc][ch * 4]);
    *(ushort4*)(dst + (size_t)(c0 + oc) * R + r0 + ch * 4) = v;
  }
}

__global__ __launch_bounds__(256) void prep_kernel(
    const float* __restrict__ W1, const float* __restrict__ W2,
    unsigned short* __restrict__ w1t, unsigned short* __restrict__ w2t,
    const float* __restrict__ x, const float* __restrict__ Wg,
    const float* __restrict__ bg, unsigned short* __restrict__ xb,
    int* __restrict__ gate_e, float* __restrict__ gate_w,
    int* __restrict__ counts, int* __restrict__ nretry,
    int* __restrict__ retry) {
  __shared__ PrepSm sm;
  int bid = blockIdx.x;
  int tid = threadIdx.x;
  if (bid < 2048) {
    // W1 [E][512][1024] -> w1t [E][1024][512]
    int cx = bid & 15, ry = (bid >> 4) & 7, mat = bid >> 7;
    transpose_body(W1 + (size_t)mat * DD * HH, w1t + (size_t)mat * DD * HH,
                   DD, HH, cx * 64, ry * 64, sm.t, tid);
    return;
  }
  if (bid < 4096) {
    // W2 [E][1024][512] -> w2t [E][512][1024]
    int b = bid - 2048;
    int cx = b & 7, ry = (b >> 3) & 15, mat = b >> 7;
    transpose_body(W2 + (size_t)mat * DD * HH, w2t + (size_t)mat * DD * HH,
                   HH, DD, cx * 64, ry * 64, sm.t, tid);
    return;
  }
  // ---- gatecv: 8 tokens per block, f32 fast path ----
  int b = bid - 4096;
  int tok0 = b * 8;
  float (*wg_s)[EE] = sm.g.wg;
  float (*x_s)[520] = sm.g.xs;
#pragma unroll
  for (int p = 0; p < 8; p++) {
    int idx = p * 256 + tid;
    ((float4*)wg_s)[idx] = ((const float4*)Wg)[idx];
  }
#pragma unroll
  for (int p = 0; p < 4; p++) {
    int f = p * 256 + tid;
    float4 v = ((const float4*)(x + (size_t)tok0 * DD))[f];
    *(float4*)&x_s[f >> 7][(f & 127) * 4] = v;
    ushort4 u;
    u.x = f2bf(v.x); u.y = f2bf(v.y); u.z = f2bf(v.z); u.w = f2bf(v.w);
    ((ushort4*)(xb + (size_t)tok0 * DD))[f] = u;
  }
  __syncthreads();
  int wv = tid >> 6, lane = tid & 63;
  int e = lane & 15, tl = (lane >> 4) & 1, ck = lane >> 5;
  int t = wv * 2 + tl;
  const float* xr = &x_s[t][ck * 256];
  float a0 = 0.f, a1 = 0.f, a2 = 0.f, a3 = 0.f;
#pragma unroll 8
  for (int i = 0; i < 64; i++) {
    float4 xv = *(const float4*)&xr[i * 4];
    int d = ck * 256 + i * 4;
    a0 += xv.x * wg_s[d + 0][e];
    a1 += xv.y * wg_s[d + 1][e];
    a2 += xv.z * wg_s[d + 2][e];
    a3 += xv.w * wg_s[d + 3][e];
  }
  float acc = (a0 + a1) + (a2 + a3);
  acc += __shfl_xor(acc, 32);      // combine d-halves
  float lf = acc + bg[e];
  float v1 = -1e30f, v2 = -1e30f, v3 = -1e30f;
  int i1 = 0, i2 = 0;
#pragma unroll
  for (int q = 0; q < EE; q++) {
    float v = __shfl(lf, (lane & 16) | q);
    if (v > v1) { v3 = v2; v2 = v1; i2 = i1; v1 = v; i1 = q; }
    else if (v > v2) { v3 = v2; v2 = v; i2 = q; }
    else if (v > v3) { v3 = v; }
  }
  if (lane == 0 || lane == 16) {
    int t2 = tok0 + t;
    float p = expf(v2 - v1);
    float s = 1.0f / (1.0f + p);
    gate_e[t2 * 2] = i1;
    gate_e[t2 * 2 + 1] = i2;
    gate_w[t2 * 2] = s;
    gate_w[t2 * 2 + 1] = p * s;
    atomicAdd(&counts[i1], 1);
    atomicAdd(&counts[i2], 1);
    if (v2 - v3 < 1e-3f) {
      int pos = atomicAdd(nretry, 1);
      if (pos < RETRYCAP) retry[pos] = t2;
    }
  }
}

// ---------------- gatefix: exact f64 recompute for near-tie tokens ----------
__global__ __launch_bounds__(256) void gatefix_kernel(
    const float* __restrict__ x, const float* __restrict__ Wg,
    const float* __restrict__ bg, const int* __restrict__ nretry,
    const int* __restrict__ retry, int* __restrict__ gate_e,
    float* __restrict__ gate_w, int* __restrict__ counts) {
  __shared__ float lg[16][17];
  __shared__ int toks[16];
  int tid = threadIdx.x;
  int sl = tid >> 4, e = tid & 15;
  int s = blockIdx.x * 16 + sl;
  int n = *nretry; if (n > RETRYCAP) n = RETRYCAP;
  int active = (s < n);
  int tok = 0;
  if (active) tok = retry[s];
  if (active) {
    const float* xr = x + (size_t)tok * DD;
    double a0 = 0.0, a1 = 0.0, a2 = 0.0, a3 = 0.0;
    for (int i = 0; i < DD / 4; i++) {
      a0 += (double)xr[i * 4 + 0] * (double)Wg[(i * 4 + 0) * EE + e];
      a1 += (double)xr[i * 4 + 1] * (double)Wg[(i * 4 + 1) * EE + e];
      a2 += (double)xr[i * 4 + 2] * (double)Wg[(i * 4 + 2) * EE + e];
      a3 += (double)xr[i * 4 + 3] * (double)Wg[(i * 4 + 3) * EE + e];
    }
    double acc = (a0 + a1) + (a2 + a3);
    lg[sl][e] = (float)(acc + (double)bg[e]);
    toks[sl] = tok;
  }
  __syncthreads();
  if (active && e == 0) {
    float v1 = -1e30f, v2 = -1e30f;
    int i1 = 0, i2 = 0;
#pragma unroll
    for (int q = 0; q < EE; q++) {
      float v = lg[sl][q];
      if (v > v1) { v2 = v1; i2 = i1; v1 = v; i1 = q; }
      else if (v > v2) { v2 = v; i2 = q; }
    }
    int t2 = toks[sl];
    int o1 = gate_e[t2 * 2], o2 = gate_e[t2 * 2 + 1];
    float p = expf(v2 - v1);
    float sc = 1.0f / (1.0f + p);
    gate_e[t2 * 2] = i1;
    gate_e[t2 * 2 + 1] = i2;
    gate_w[t2 * 2] = sc;
    gate_w[t2 * 2 + 1] = p * sc;
    if (o1 != i1 || o2 != i2) {
      atomicSub(&counts[o1], 1);
      atomicSub(&counts[o2], 1);
      atomicAdd(&counts[i1], 1);
      atomicAdd(&counts[i2], 1);
    }
  }
}

// ---------------- route: scan + scatter fused (single block) ----------------
__global__ __launch_bounds__(256) void route_kernel(
    const int* __restrict__ gate_e, const float* __restrict__ gate_w,
    const int* __restrict__ counts, int* __restrict__ tile_expert,
    int* __restrict__ ntiles, int* __restrict__ slot_token,
    float* __restrict__ slot_w, int* __restrict__ slot_of) {
  __shared__ int offs_s[EE + 1];
  __shared__ int fill_s[EE];
  int tid = threadIdx.x;
  for (int i = tid; i < NSLOT; i += 256) slot_token[i] = -1;
  if (tid == 0) {
    int off = 0, nt = 0;
    for (int e = 0; e < EE; e++) {
      offs_s[e] = off;
      fill_s[e] = 0;
      int tiles = (counts[e] + BM - 1) / BM;
      for (int t = 0; t < tiles; t++) tile_expert[nt++] = e;
      off += tiles * BM;
    }
    offs_s[EE] = off;
    ntiles[0] = nt;
  }
  __syncthreads();
  for (int t = tid; t < TT; t += 256) {
#pragma unroll
    for (int k = 0; k < 2; k++) {
      int e = gate_e[t * 2 + k];
      int pos = atomicAdd(&fill_s[e], 1);
      int slot = offs_s[e] + pos;
      slot_token[slot] = t;
      slot_w[slot] = gate_w[t * 2 + k];
      slot_of[t * 2 + k] = slot;
    }
  }
}

// ---------------- GEMM1: h = gelu(x[slot] @ W1[e] + b1[e]) ----------------
// grid (HH/128, MAXTILES): wgid = mt*8+n0 -> XCD = n0 -> same-n0 blocks
// (sharing B panels, 16*128KB=2MB) co-locate per XCD L2.
__global__ __launch_bounds__(256) void gemm1_kernel(
    const unsigned short* __restrict__ xb, const unsigned short* __restrict__ w1t,
    const float* __restrict__ b1, const int* __restrict__ slot_token,
    const int* __restrict__ tile_expert, const int* __restrict__ ntiles,
    unsigned short* __restrict__ hb) {
  int mt = blockIdx.y;
  if (mt >= ntiles[0]) return;
  int e = tile_expert[mt];
  int row0 = mt * BM;
  int n0 = blockIdx.x * 128;
  __shared__ unsigned short As[128][32];
  __shared__ unsigned short Bs[128][32];
  int tid = threadIdx.x;
  int lane = tid & 63;
  int wave = tid >> 6;
  int wm = wave >> 1, wn = wave & 1;
  int ra = tid >> 2, c = tid & 3;
  int tok_a = slot_token[row0 + ra]; if (tok_a < 0) tok_a = 0;
  int tok_b = slot_token[row0 + ra + 64]; if (tok_b < 0) tok_b = 0;
  const unsigned short* wbase = w1t + ((size_t)e * HH * DD);
  f32x4 acc[4][4];
#pragma unroll
  for (int m = 0; m < 4; m++)
#pragma unroll
    for (int n = 0; n < 4; n++) {
      f32x4 z = {0.f, 0.f, 0.f, 0.f};
      acc[m][n] = z;
    }
  for (int kk = 0; kk < DD / 32; kk++) {
    int k0 = kk * 32;
    __syncthreads();
    gload16(xb + (size_t)tok_a * DD + k0 + c * 8, &As[ra][c * 8]);
    gload16(xb + (size_t)tok_b * DD + k0 + c * 8, &As[ra + 64][c * 8]);
    gload16(wbase + (size_t)(n0 + ra) * DD + k0 + c * 8, &Bs[ra][c * 8]);
    gload16(wbase + (size_t)(n0 + ra + 64) * DD + k0 + c * 8, &Bs[ra + 64][c * 8]);
    __syncthreads();
    bf16x8 a[4], b[4];
#pragma unroll
    for (int m = 0; m < 4; m++)
      a[m] = *(const bf16x8*)(&As[wm * 64 + m * 16 + (lane & 15)][(lane >> 4) * 8]);
#pragma unroll
    for (int n = 0; n < 4; n++)
      b[n] = *(const bf16x8*)(&Bs[wn * 64 + n * 16 + (lane & 15)][(lane >> 4) * 8]);
#pragma unroll
    for (int m = 0; m < 4; m++)
#pragma unroll
      for (int n = 0; n < 4; n++)
        acc[m][n] = __builtin_amdgcn_mfma_f32_16x16x32_bf16(a[m], b[n], acc[m][n], 0, 0, 0);
  }
  const float* b1e = b1 + (size_t)e * HH;
#pragma unroll
  for (int m = 0; m < 4; m++) {
#pragma unroll
    for (int r = 0; r < 4; r++) {
      int slot = row0 + wm * 64 + m * 16 + ((lane >> 4) << 2) + r;
      unsigned short* hrow = hb + (size_t)slot * HH;
#pragma unroll
      for (int n = 0; n < 4; n++) {
        int hc = n0 + wn * 64 + n * 16 + (lane & 15);
        float v = acc[m][n][r] + b1e[hc];
        hrow[hc] = f2bf(gelu_f(v));
      }
    }
  }
}

// ---------------- GEMM2: yw[slot] = w*(h[slot] @ W2[e] + b2[e]) ----------------
template <int USE_Y>
__global__ __launch_bounds__(256) void gemm2_kernel(
    const unsigned short* __restrict__ hb, const unsigned short* __restrict__ w2t,
    const float* __restrict__ b2, const int* __restrict__ slot_token,
    const float* __restrict__ slot_w, const int* __restrict__ tile_expert,
    const int* __restrict__ ntiles, unsigned short* __restrict__ yw,
    float* __restrict__ out) {
  int mt = blockIdx.y;
  if (mt >= ntiles[0]) return;
  int e = tile_expert[mt];
  int row0 = mt * BM;
  int n0 = blockIdx.x * 128;
  __shared__ unsigned short As[128][32];
  __shared__ unsigned short Bs[128][32];
  int tid = threadIdx.x;
  int lane = tid & 63;
  int wave = tid >> 6;
  int wm = wave >> 1, wn = wave & 1;
  int ra = tid >> 2, c = tid & 3;
  const unsigned short* wbase = w2t + ((size_t)e * DD * HH);
  f32x4 acc[4][4];
#pragma unroll
  for (int m = 0; m < 4; m++)
#pragma unroll
    for (int n = 0; n < 4; n++) {
      f32x4 z = {0.f, 0.f, 0.f, 0.f};
      acc[m][n] = z;
    }
  for (int kk = 0; kk < HH / 32; kk++) {
    int k0 = kk * 32;
    __syncthreads();
    gload16(hb + (size_t)(row0 + ra) * HH + k0 + c * 8, &As[ra][c * 8]);
    gload16(hb + (size_t)(row0 + ra + 64) * HH + k0 + c * 8, &As[ra + 64][c * 8]);
    gload16(wbase + (size_t)(n0 + ra) * HH + k0 + c * 8, &Bs[ra][c * 8]);
    gload16(wbase + (size_t)(n0 + ra + 64) * HH + k0 + c * 8, &Bs[ra + 64][c * 8]);
    __syncthreads();
    bf16x8 a[4], b[4];
#pragma unroll
    for (int m = 0; m < 4; m++)
      a[m] = *(const bf16x8*)(&As[wm * 64 + m * 16 + (lane & 15)][(lane >> 4) * 8]);
#pragma unroll
    for (int n = 0; n < 4; n++)
      b[n] = *(const bf16x8*)(&Bs[wn * 64 + n * 16 + (lane & 15)][(lane >> 4) * 8]);
#pragma unroll
    for (int m = 0; m < 4; m++)
#pragma unroll
      for (int n = 0; n < 4; n++)
        acc[m][n] = __builtin_amdgcn_mfma_f32_16x16x32_bf16(a[m], b[n], acc[m][n], 0, 0, 0);
  }
  const float* b2e = b2 + (size_t)e * DD;
#pragma unroll
  for (int m = 0; m < 4; m++) {
#pragma unroll
    for (int r = 0; r < 4; r++) {
      int slot = row0 + wm * 64 + m * 16 + ((lane >> 4) << 2) + r;
      if (USE_Y) {
        float w = slot_w[slot];
        unsigned short* yrow = yw + (size_t)slot * DD;
#pragma unroll
        for (int n = 0; n < 4; n++) {
          int dc = n0 + wn * 64 + n * 16 + (lane & 15);
          yrow[dc] = f2bf(w * (acc[m][n][r] + b2e[dc]));
        }
      } else {
        int tok = slot_token[slot];
        if (tok >= 0) {
          float w = slot_w[slot];
          float* orow = out + (size_t)tok * DD;
#pragma unroll
          for (int n = 0; n < 4; n++) {
            int dc = n0 + wn * 64 + n * 16 + (lane & 15);
            float v = acc[m][n][r] + b2e[dc];
            atomicAdd(&orow[dc], w * v);
          }
        }
      }
    }
  }
}

// ---------------- combine: out[t] = yw[s1] + yw[s2] ----------------
__global__ __launch_bounds__(256) void combine_kernel(
    const unsigned short* __restrict__ yw, const int* __restrict__ slot_of,
    float* __restrict__ out) {
  int gid = blockIdx.x * 256 + threadIdx.x;
  int t = gid >> 6;
  int d0 = (gid & 63) * 8;
  int s1 = slot_of[t * 2], s2 = slot_of[t * 2 + 1];
  const ushort4* p1 = (const ushort4*)(yw + (size_t)s1 * DD + d0);
  const ushort4* p2 = (const ushort4*)(yw + (size_t)s2 * DD + d0);
  ushort4 a0 = p1[0], a1 = p1[1];
  ushort4 b0 = p2[0], b1 = p2[1];
  float4 o0, o1;
  o0.x = bf2f(a0.x) + bf2f(b0.x);
  o0.y = bf2f(a0.y) + bf2f(b0.y);
  o0.z = bf2f(a0.z) + bf2f(b0.z);
  o0.w = bf2f(a0.w) + bf2f(b0.w);
  o1.x = bf2f(a1.x) + bf2f(b1.x);
  o1.y = bf2f(a1.y) + bf2f(b1.y);
  o1.z = bf2f(a1.z) + bf2f(b1.z);
  o1.w = bf2f(a1.w) + bf2f(b1.w);
  float* orow = out + (size_t)t * DD + d0;
  ((float4*)orow)[0] = o0;
  ((float4*)orow)[1] = o1;
}

extern "C" void kernel_launch(void* const* d_in, const int* in_sizes, int n_in,
                              void* d_out, int out_size, void* d_ws, size_t ws_size,
                              hipStream_t stream) {
  const float* x  = (const float*)d_in[0];
  const float* Wg = (const float*)d_in[1];
  const float* bg = (const float*)d_in[2];
  const float* W1 = (const float*)d_in[3];
  const float* b1 = (const float*)d_in[4];
  const float* W2 = (const float*)d_in[5];
  const float* b2 = (const float*)d_in[6];
  float* out = (float*)d_out;

  uint8_t* w = (uint8_t*)d_ws;
  size_t o = 0;
  unsigned short* xb  = (unsigned short*)(w + o); o += (size_t)TT * DD * 2;       // 8 MB
  unsigned short* w1t = (unsigned short*)(w + o); o += (size_t)EE * DD * HH * 2;  // 16 MB
  unsigned short* w2t = (unsigned short*)(w + o); o += (size_t)EE * DD * HH * 2;  // 16 MB
  unsigned short* hb  = (unsigned short*)(w + o); o += (size_t)NSLOT * HH * 2;    // 37.7 MB
  int*   slot_token = (int*)(w + o);   o += (size_t)NSLOT * 4;
  float* slot_w     = (float*)(w + o); o += (size_t)NSLOT * 4;
  int*   slot_of    = (int*)(w + o);   o += (size_t)TT * 2 * 4;
  int*   gate_e     = (int*)(w + o);   o += (size_t)TT * 2 * 4;
  float* gate_w     = (float*)(w + o); o += (size_t)TT * 2 * 4;
  int*   counts     = (int*)(w + o);   o += 64;   // counts[16]
  int*   nretry     = (int*)(w + o);   o += 64;   // adjacent: one 128B memset
  int*   tile_expert= (int*)(w + o);   o += 640;
  int*   ntiles     = (int*)(w + o);   o += 64;
  int*   retry      = (int*)(w + o);   o += RETRYCAP * 4;
  unsigned short* yw = (unsigned short*)(w + o);
  size_t need_y = o + (size_t)NSLOT * DD * 2;   // +18.9 MB
  int use_y = (ws_size >= need_y);

  hipMemsetAsync(counts, 0, 128, stream);  // counts + nretry
  if (!use_y) hipMemsetAsync(d_out, 0, (size_t)TT * DD * 4, stream);

  // transposes + gatecv, one launch (independent work overlaps)
  prep_kernel<<<4096 + TT / 8, 256, 0, stream>>>(
      W1, W2, w1t, w2t, x, Wg, bg, xb, gate_e, gate_w, counts, nretry, retry);
  gatefix_kernel<<<RETRYCAP / 16, 256, 0, stream>>>(x, Wg, bg, nretry, retry,
                                                    gate_e, gate_w, counts);
  route_kernel<<<1, 256, 0, stream>>>(gate_e, gate_w, counts, tile_expert,
                                      ntiles, slot_token, slot_w, slot_of);
  {
    dim3 g(HH / 128, MAXTILES);
    gemm1_kernel<<<g, 256, 0, stream>>>(xb, w1t, b1, slot_token, tile_expert, ntiles, hb);
  }
  {
    dim3 g(DD / 128, MAXTILES);
    if (use_y)
      gemm2_kernel<1><<<g, 256, 0, stream>>>(hb, w2t, b2, slot_token, slot_w,
                                             tile_expert, ntiles, yw, out);
    else
      gemm2_kernel<0><<<g, 256, 0, stream>>>(hb, w2t, b2, slot_token, slot_w,
                                             tile_expert, ntiles, yw, out);
  }
  if (use_y) {
    combine_kernel<<<TT * (DD / 8) / 256, 256, 0, stream>>>(yw, slot_of, out);
  }
}

// Round 8
// 208.621 us; speedup vs baseline: 1.3289x; 1.3289x over previous
//
#include <hip/hip_runtime.h>
#include <hip/hip_bf16.h>
#include <math.h>

#define TT 8192
#define DD 512
#define HH 1024
#define EE 16
#define NSLOT 18432   // 144 * 128 max padded slots
#define MAXTILES 144
#define BM 128
#define RETRYCAP 1024

typedef __attribute__((ext_vector_type(8))) short bf16x8;
typedef __attribute__((ext_vector_type(8))) unsigned short u16x8;
typedef __attribute__((ext_vector_type(4))) float f32x4;

__device__ __forceinline__ unsigned short f2bf(float f) {
  union { float f; unsigned u; } v; v.f = f;
  unsigned r = v.u + 0x7fffu + ((v.u >> 16) & 1u);
  return (unsigned short)(r >> 16);
}

__device__ __forceinline__ float bf2f(unsigned short u) {
  union { unsigned u; float f; } v; v.u = ((unsigned)u) << 16;
  return v.f;
}

__device__ __forceinline__ void gload16(const void* g, void* l) {
  __builtin_amdgcn_global_load_lds(
      (const __attribute__((address_space(1))) unsigned int*)g,
      (__attribute__((address_space(3))) unsigned int*)l, 16, 0, 0);
}

// Abramowitz-Stegun 7.1.26 erf approx (|err| <= 1.5e-7), ~12 VALU ops
__device__ __forceinline__ float gelu_f(float v) {
  float s = fabsf(v) * 0.70710678118654752f;
  float t = 1.0f / (1.0f + 0.3275911f * s);
  float poly = t * (0.254829592f +
              t * (-0.284496736f +
              t * (1.421413741f +
              t * (-1.453152027f +
              t * 1.061405429f))));
  float erfa = 1.0f - poly * __expf(-s * s);
  float erfv = (v >= 0.f) ? erfa : -erfa;
  return 0.5f * v * (1.0f + erfv);
}

// ------- transpose+convert: in f32 [nmat][R][C] -> out bf16 [nmat][C][R] -------
__global__ __launch_bounds__(256) void transpose_cv_kernel(
    const float* __restrict__ in, unsigned short* __restrict__ out, int R, int C) {
  int mat = blockIdx.z;
  int c0 = blockIdx.x * 64;
  int r0 = blockIdx.y * 64;
  const float* src = in + (size_t)mat * R * C;
  unsigned short* dst = out + (size_t)mat * R * C;
  __shared__ unsigned short t[64][68];
  int tid = threadIdx.x;
#pragma unroll
  for (int p = 0; p < 4; p++) {
    int r = tid >> 2;
    int c4 = (tid & 3) + p * 4;
    float4 v = *(const float4*)(src + (size_t)(r0 + r) * C + c0 + c4 * 4);
    t[c4 * 4 + 0][r] = f2bf(v.x);
    t[c4 * 4 + 1][r] = f2bf(v.y);
    t[c4 * 4 + 2][r] = f2bf(v.z);
    t[c4 * 4 + 3][r] = f2bf(v.w);
  }
  __syncthreads();
#pragma unroll
  for (int p = 0; p < 4; p++) {
    int oc = (tid >> 4) + p * 16;
    int ch = tid & 15;
    ushort4 v = *(ushort4*)(&t[oc][ch * 4]);
    *(ushort4*)(dst + (size_t)(c0 + oc) * R + r0 + ch * 4) = v;
  }
}

// ---------------- gate via MFMA: logits = x @ Wg (bf16), fused x->xb convert ----
// 64 blocks x 128 tokens, 4 waves. Wg^T B-fragments live in registers (16x
// bf16x8). Per K-step: stage x f32->bf16 tile in LDS + write xb, 2 MFMAs/wave.
// Top-3 per token via lane broadcasts; near-ties (gap < 0.02 ~ 7 sigma of
// bf16 logit error) queued for exact f64 repair in gatefix.
__global__ __launch_bounds__(256) void gate_mfma_kernel(
    const float* __restrict__ x, const float* __restrict__ Wg,
    const float* __restrict__ bg, unsigned short* __restrict__ xb,
    int* __restrict__ gate_e, float* __restrict__ gate_w,
    int* __restrict__ counts, int* __restrict__ nretry,
    int* __restrict__ retry) {
  __shared__ __align__(16) unsigned short As[128][40];  // 80B rows, 16B-aligned
  __shared__ int cnt_s[EE];
  int tid = threadIdx.x;
  int lane = tid & 63;
  int wave = tid >> 6;
  int tok0 = blockIdx.x * 128;
  if (tid < EE) cnt_s[tid] = 0;
  int e = lane & 15;
  int kb = (lane >> 4) * 8;
  // B fragments: bfrag[ks][j] = Wg[(ks*32 + kb + j)][e], bf16
  bf16x8 bfrag[16];
#pragma unroll
  for (int ks = 0; ks < 16; ks++) {
    int kbase = ks * 32 + kb;
#pragma unroll
    for (int j = 0; j < 8; j++)
      bfrag[ks][j] = (short)f2bf(Wg[(kbase + j) * EE + e]);
  }
  float bge = bg[e];
  f32x4 acc[2];
  {
    f32x4 z = {0.f, 0.f, 0.f, 0.f};
    acc[0] = z; acc[1] = z;
  }
  int srow = tid >> 1;           // 0..127
  int sc0 = (tid & 1) * 16;      // 0 or 16
  const float* xrow = x + (size_t)(tok0 + srow) * DD + sc0;
  unsigned short* xbrow = xb + (size_t)(tok0 + srow) * DD + sc0;
  for (int ks = 0; ks < 16; ks++) {
    int k0 = ks * 32;
    __syncthreads();   // previous iter's reads done before overwrite
    float4 v0 = *(const float4*)(xrow + k0);
    float4 v1 = *(const float4*)(xrow + k0 + 4);
    float4 v2 = *(const float4*)(xrow + k0 + 8);
    float4 v3 = *(const float4*)(xrow + k0 + 12);
    u16x8 w0, w1;
    w0[0] = f2bf(v0.x); w0[1] = f2bf(v0.y); w0[2] = f2bf(v0.z); w0[3] = f2bf(v0.w);
    w0[4] = f2bf(v1.x); w0[5] = f2bf(v1.y); w0[6] = f2bf(v1.z); w0[7] = f2bf(v1.w);
    w1[0] = f2bf(v2.x); w1[1] = f2bf(v2.y); w1[2] = f2bf(v2.z); w1[3] = f2bf(v2.w);
    w1[4] = f2bf(v3.x); w1[5] = f2bf(v3.y); w1[6] = f2bf(v3.z); w1[7] = f2bf(v3.w);
    *(u16x8*)(xbrow + k0) = w0;
    *(u16x8*)(xbrow + k0 + 8) = w1;
    *(u16x8*)(&As[srow][sc0]) = w0;
    *(u16x8*)(&As[srow][sc0 + 8]) = w1;
    __syncthreads();
    bf16x8 a0 = *(const bf16x8*)(&As[wave * 32 + (lane & 15)][kb]);
    bf16x8 a1 = *(const bf16x8*)(&As[wave * 32 + 16 + (lane & 15)][kb]);
    acc[0] = __builtin_amdgcn_mfma_f32_16x16x32_bf16(a0, bfrag[ks], acc[0], 0, 0, 0);
    acc[1] = __builtin_amdgcn_mfma_f32_16x16x32_bf16(a1, bfrag[ks], acc[1], 0, 0, 0);
  }
#pragma unroll
  for (int m = 0; m < 2; m++) {
#pragma unroll
    for (int r = 0; r < 4; r++) {
      float lf = acc[m][r] + bge;
      float v1 = -1e30f, v2 = -1e30f, v3 = -1e30f;
      int i1 = 0, i2 = 0;
#pragma unroll
      for (int q = 0; q < EE; q++) {
        float v = __shfl(lf, (lane & 48) | q);
        if (v > v1) { v3 = v2; v2 = v1; i2 = i1; v1 = v; i1 = q; }
        else if (v > v2) { v3 = v2; v2 = v; i2 = q; }
        else if (v > v3) { v3 = v; }
      }
      if ((lane & 15) == 0) {
        int t2 = tok0 + wave * 32 + m * 16 + ((lane >> 4) << 2) + r;
        float p = expf(v2 - v1);
        float s = 1.0f / (1.0f + p);
        gate_e[t2 * 2] = i1;
        gate_e[t2 * 2 + 1] = i2;
        gate_w[t2 * 2] = s;
        gate_w[t2 * 2 + 1] = p * s;
        atomicAdd(&cnt_s[i1], 1);
        atomicAdd(&cnt_s[i2], 1);
        if (v2 - v3 < 0.02f) {
          int pos = atomicAdd(nretry, 1);
          if (pos < RETRYCAP) retry[pos] = t2;
        }
      }
    }
  }
  __syncthreads();
  if (tid < EE) atomicAdd(&counts[tid], cnt_s[tid]);
}

// ---------------- gatefix: exact f64 recompute for near-tie tokens ----------
__global__ __launch_bounds__(256) void gatefix_kernel(
    const float* __restrict__ x, const float* __restrict__ Wg,
    const float* __restrict__ bg, const int* __restrict__ nretry,
    const int* __restrict__ retry, int* __restrict__ gate_e,
    float* __restrict__ gate_w, int* __restrict__ counts) {
  __shared__ float lg[16][17];
  __shared__ int toks[16];
  int tid = threadIdx.x;
  int sl = tid >> 4, e = tid & 15;
  int s = blockIdx.x * 16 + sl;
  int n = *nretry; if (n > RETRYCAP) n = RETRYCAP;
  int active = (s < n);
  int tok = 0;
  if (active) tok = retry[s];
  if (active) {
    const float* xr = x + (size_t)tok * DD;
    double a0 = 0.0, a1 = 0.0, a2 = 0.0, a3 = 0.0;
    for (int i = 0; i < DD / 4; i++) {
      a0 += (double)xr[i * 4 + 0] * (double)Wg[(i * 4 + 0) * EE + e];
      a1 += (double)xr[i * 4 + 1] * (double)Wg[(i * 4 + 1) * EE + e];
      a2 += (double)xr[i * 4 + 2] * (double)Wg[(i * 4 + 2) * EE + e];
      a3 += (double)xr[i * 4 + 3] * (double)Wg[(i * 4 + 3) * EE + e];
    }
    double acc = (a0 + a1) + (a2 + a3);
    lg[sl][e] = (float)(acc + (double)bg[e]);
    toks[sl] = tok;
  }
  __syncthreads();
  if (active && e == 0) {
    float v1 = -1e30f, v2 = -1e30f;
    int i1 = 0, i2 = 0;
#pragma unroll
    for (int q = 0; q < EE; q++) {
      float v = lg[sl][q];
      if (v > v1) { v2 = v1; i2 = i1; v1 = v; i1 = q; }
      else if (v > v2) { v2 = v; i2 = q; }
    }
    int t2 = toks[sl];
    int o1 = gate_e[t2 * 2], o2 = gate_e[t2 * 2 + 1];
    float p = expf(v2 - v1);
    float sc = 1.0f / (1.0f + p);
    gate_e[t2 * 2] = i1;
    gate_e[t2 * 2 + 1] = i2;
    gate_w[t2 * 2] = sc;
    gate_w[t2 * 2 + 1] = p * sc;
    if (o1 != i1 || o2 != i2) {
      atomicSub(&counts[o1], 1);
      atomicSub(&counts[o2], 1);
      atomicAdd(&counts[i1], 1);
      atomicAdd(&counts[i2], 1);
    }
  }
}

// ---------------- route: scan + scatter fused (single block) ----------------
__global__ __launch_bounds__(256) void route_kernel(
    const int* __restrict__ gate_e, const float* __restrict__ gate_w,
    const int* __restrict__ counts, int* __restrict__ tile_expert,
    int* __restrict__ ntiles, int* __restrict__ slot_token,
    float* __restrict__ slot_w, int* __restrict__ slot_of) {
  __shared__ int offs_s[EE + 1];
  __shared__ int fill_s[EE];
  int tid = threadIdx.x;
  for (int i = tid; i < NSLOT; i += 256) slot_token[i] = -1;
  if (tid == 0) {
    int off = 0, nt = 0;
    for (int e = 0; e < EE; e++) {
      offs_s[e] = off;
      fill_s[e] = 0;
      int tiles = (counts[e] + BM - 1) / BM;
      for (int t = 0; t < tiles; t++) tile_expert[nt++] = e;
      off += tiles * BM;
    }
    offs_s[EE] = off;
    ntiles[0] = nt;
  }
  __syncthreads();
  for (int t = tid; t < TT; t += 256) {
#pragma unroll
    for (int k = 0; k < 2; k++) {
      int e = gate_e[t * 2 + k];
      int pos = atomicAdd(&fill_s[e], 1);
      int slot = offs_s[e] + pos;
      slot_token[slot] = t;
      slot_w[slot] = gate_w[t * 2 + k];
      slot_of[t * 2 + k] = slot;
    }
  }
}

// ---------------- GEMM1: h = gelu(x[slot] @ W1[e] + b1[e]) ----------------
// grid (HH/128, MAXTILES): wgid = mt*8+n0 -> XCD = n0 -> same-n0 blocks
// (sharing B panels, 16*128KB=2MB) co-locate per XCD L2.
__global__ __launch_bounds__(256) void gemm1_kernel(
    const unsigned short* __restrict__ xb, const unsigned short* __restrict__ w1t,
    const float* __restrict__ b1, const int* __restrict__ slot_token,
    const int* __restrict__ tile_expert, const int* __restrict__ ntiles,
    unsigned short* __restrict__ hb) {
  int mt = blockIdx.y;
  if (mt >= ntiles[0]) return;
  int e = tile_expert[mt];
  int row0 = mt * BM;
  int n0 = blockIdx.x * 128;
  __shared__ unsigned short As[128][32];
  __shared__ unsigned short Bs[128][32];
  int tid = threadIdx.x;
  int lane = tid & 63;
  int wave = tid >> 6;
  int wm = wave >> 1, wn = wave & 1;
  int ra = tid >> 2, c = tid & 3;
  int tok_a = slot_token[row0 + ra]; if (tok_a < 0) tok_a = 0;
  int tok_b = slot_token[row0 + ra + 64]; if (tok_b < 0) tok_b = 0;
  const unsigned short* wbase = w1t + ((size_t)e * HH * DD);
  f32x4 acc[4][4];
#pragma unroll
  for (int m = 0; m < 4; m++)
#pragma unroll
    for (int n = 0; n < 4; n++) {
      f32x4 z = {0.f, 0.f, 0.f, 0.f};
      acc[m][n] = z;
    }
  for (int kk = 0; kk < DD / 32; kk++) {
    int k0 = kk * 32;
    __syncthreads();
    gload16(xb + (size_t)tok_a * DD + k0 + c * 8, &As[ra][c * 8]);
    gload16(xb + (size_t)tok_b * DD + k0 + c * 8, &As[ra + 64][c * 8]);
    gload16(wbase + (size_t)(n0 + ra) * DD + k0 + c * 8, &Bs[ra][c * 8]);
    gload16(wbase + (size_t)(n0 + ra + 64) * DD + k0 + c * 8, &Bs[ra + 64][c * 8]);
    __syncthreads();
    bf16x8 a[4], b[4];
#pragma unroll
    for (int m = 0; m < 4; m++)
      a[m] = *(const bf16x8*)(&As[wm * 64 + m * 16 + (lane & 15)][(lane >> 4) * 8]);
#pragma unroll
    for (int n = 0; n < 4; n++)
      b[n] = *(const bf16x8*)(&Bs[wn * 64 + n * 16 + (lane & 15)][(lane >> 4) * 8]);
#pragma unroll
    for (int m = 0; m < 4; m++)
#pragma unroll
      for (int n = 0; n < 4; n++)
        acc[m][n] = __builtin_amdgcn_mfma_f32_16x16x32_bf16(a[m], b[n], acc[m][n], 0, 0, 0);
  }
  const float* b1e = b1 + (size_t)e * HH;
#pragma unroll
  for (int m = 0; m < 4; m++) {
#pragma unroll
    for (int r = 0; r < 4; r++) {
      int slot = row0 + wm * 64 + m * 16 + ((lane >> 4) << 2) + r;
      unsigned short* hrow = hb + (size_t)slot * HH;
#pragma unroll
      for (int n = 0; n < 4; n++) {
        int hc = n0 + wn * 64 + n * 16 + (lane & 15);
        float v = acc[m][n][r] + b1e[hc];
        hrow[hc] = f2bf(gelu_f(v));
      }
    }
  }
}

// ---------------- GEMM2: yw[slot] = w*(h[slot] @ W2[e] + b2[e]) ----------------
template <int USE_Y>
__global__ __launch_bounds__(256) void gemm2_kernel(
    const unsigned short* __restrict__ hb, const unsigned short* __restrict__ w2t,
    const float* __restrict__ b2, const int* __restrict__ slot_token,
    const float* __restrict__ slot_w, const int* __restrict__ tile_expert,
    const int* __restrict__ ntiles, unsigned short* __restrict__ yw,
    float* __restrict__ out) {
  int mt = blockIdx.y;
  if (mt >= ntiles[0]) return;
  int e = tile_expert[mt];
  int row0 = mt * BM;
  int n0 = blockIdx.x * 128;
  __shared__ unsigned short As[128][32];
  __shared__ unsigned short Bs[128][32];
  int tid = threadIdx.x;
  int lane = tid & 63;
  int wave = tid >> 6;
  int wm = wave >> 1, wn = wave & 1;
  int ra = tid >> 2, c = tid & 3;
  const unsigned short* wbase = w2t + ((size_t)e * DD * HH);
  f32x4 acc[4][4];
#pragma unroll
  for (int m = 0; m < 4; m++)
#pragma unroll
    for (int n = 0; n < 4; n++) {
      f32x4 z = {0.f, 0.f, 0.f, 0.f};
      acc[m][n] = z;
    }
  for (int kk = 0; kk < HH / 32; kk++) {
    int k0 = kk * 32;
    __syncthreads();
    gload16(hb + (size_t)(row0 + ra) * HH + k0 + c * 8, &As[ra][c * 8]);
    gload16(hb + (size_t)(row0 + ra + 64) * HH + k0 + c * 8, &As[ra + 64][c * 8]);
    gload16(wbase + (size_t)(n0 + ra) * HH + k0 + c * 8, &Bs[ra][c * 8]);
    gload16(wbase + (size_t)(n0 + ra + 64) * HH + k0 + c * 8, &Bs[ra + 64][c * 8]);
    __syncthreads();
    bf16x8 a[4], b[4];
#pragma unroll
    for (int m = 0; m < 4; m++)
      a[m] = *(const bf16x8*)(&As[wm * 64 + m * 16 + (lane & 15)][(lane >> 4) * 8]);
#pragma unroll
    for (int n = 0; n < 4; n++)
      b[n] = *(const bf16x8*)(&Bs[wn * 64 + n * 16 + (lane & 15)][(lane >> 4) * 8]);
#pragma unroll
    for (int m = 0; m < 4; m++)
#pragma unroll
      for (int n = 0; n < 4; n++)
        acc[m][n] = __builtin_amdgcn_mfma_f32_16x16x32_bf16(a[m], b[n], acc[m][n], 0, 0, 0);
  }
  const float* b2e = b2 + (size_t)e * DD;
#pragma unroll
  for (int m = 0; m < 4; m++) {
#pragma unroll
    for (int r = 0; r < 4; r++) {
      int slot = row0 + wm * 64 + m * 16 + ((lane >> 4) << 2) + r;
      if (USE_Y) {
        float w = slot_w[slot];
        unsigned short* yrow = yw + (size_t)slot * DD;
#pragma unroll
        for (int n = 0; n < 4; n++) {
          int dc = n0 + wn * 64 + n * 16 + (lane & 15);
          yrow[dc] = f2bf(w * (acc[m][n][r] + b2e[dc]));
        }
      } else {
        int tok = slot_token[slot];
        if (tok >= 0) {
          float w = slot_w[slot];
          float* orow = out + (size_t)tok * DD;
#pragma unroll
          for (int n = 0; n < 4; n++) {
            int dc = n0 + wn * 64 + n * 16 + (lane & 15);
            float v = acc[m][n][r] + b2e[dc];
            atomicAdd(&orow[dc], w * v);
          }
        }
      }
    }
  }
}

// ---------------- combine: out[t] = yw[s1] + yw[s2] ----------------
__global__ __launch_bounds__(256) void combine_kernel(
    const unsigned short* __restrict__ yw, const int* __restrict__ slot_of,
    float* __restrict__ out) {
  int gid = blockIdx.x * 256 + threadIdx.x;
  int t = gid >> 6;
  int d0 = (gid & 63) * 8;
  int s1 = slot_of[t * 2], s2 = slot_of[t * 2 + 1];
  const ushort4* p1 = (const ushort4*)(yw + (size_t)s1 * DD + d0);
  const ushort4* p2 = (const ushort4*)(yw + (size_t)s2 * DD + d0);
  ushort4 a0 = p1[0], a1 = p1[1];
  ushort4 b0 = p2[0], b1 = p2[1];
  float4 o0, o1;
  o0.x = bf2f(a0.x) + bf2f(b0.x);
  o0.y = bf2f(a0.y) + bf2f(b0.y);
  o0.z = bf2f(a0.z) + bf2f(b0.z);
  o0.w = bf2f(a0.w) + bf2f(b0.w);
  o1.x = bf2f(a1.x) + bf2f(b1.x);
  o1.y = bf2f(a1.y) + bf2f(b1.y);
  o1.z = bf2f(a1.z) + bf2f(b1.z);
  o1.w = bf2f(a1.w) + bf2f(b1.w);
  float* orow = out + (size_t)t * DD + d0;
  ((float4*)orow)[0] = o0;
  ((float4*)orow)[1] = o1;
}

extern "C" void kernel_launch(void* const* d_in, const int* in_sizes, int n_in,
                              void* d_out, int out_size, void* d_ws, size_t ws_size,
                              hipStream_t stream) {
  const float* x  = (const float*)d_in[0];
  const float* Wg = (const float*)d_in[1];
  const float* bg = (const float*)d_in[2];
  const float* W1 = (const float*)d_in[3];
  const float* b1 = (const float*)d_in[4];
  const float* W2 = (const float*)d_in[5];
  const float* b2 = (const float*)d_in[6];
  float* out = (float*)d_out;

  uint8_t* w = (uint8_t*)d_ws;
  size_t o = 0;
  unsigned short* xb  = (unsigned short*)(w + o); o += (size_t)TT * DD * 2;       // 8 MB
  unsigned short* w1t = (unsigned short*)(w + o); o += (size_t)EE * DD * HH * 2;  // 16 MB
  unsigned short* w2t = (unsigned short*)(w + o); o += (size_t)EE * DD * HH * 2;  // 16 MB
  unsigned short* hb  = (unsigned short*)(w + o); o += (size_t)NSLOT * HH * 2;    // 37.7 MB
  int*   slot_token = (int*)(w + o);   o += (size_t)NSLOT * 4;
  float* slot_w     = (float*)(w + o); o += (size_t)NSLOT * 4;
  int*   slot_of    = (int*)(w + o);   o += (size_t)TT * 2 * 4;
  int*   gate_e     = (int*)(w + o);   o += (size_t)TT * 2 * 4;
  float* gate_w     = (float*)(w + o); o += (size_t)TT * 2 * 4;
  int*   counts     = (int*)(w + o);   o += 64;   // counts[16]
  int*   nretry     = (int*)(w + o);   o += 64;   // adjacent: one 128B memset
  int*   tile_expert= (int*)(w + o);   o += 640;
  int*   ntiles     = (int*)(w + o);   o += 64;
  int*   retry      = (int*)(w + o);   o += RETRYCAP * 4;
  unsigned short* yw = (unsigned short*)(w + o);
  size_t need_y = o + (size_t)NSLOT * DD * 2;   // +18.9 MB
  int use_y = (ws_size >= need_y);

  hipMemsetAsync(counts, 0, 128, stream);  // counts + nretry
  if (!use_y) hipMemsetAsync(d_out, 0, (size_t)TT * DD * 4, stream);

  // W1 [E][512][1024] -> w1t [E][1024][512]
  {
    dim3 g(HH / 64, DD / 64, EE);
    transpose_cv_kernel<<<g, 256, 0, stream>>>(W1, w1t, DD, HH);
  }
  // W2 [E][1024][512] -> w2t [E][512][1024]
  {
    dim3 g(DD / 64, HH / 64, EE);
    transpose_cv_kernel<<<g, 256, 0, stream>>>(W2, w2t, HH, DD);
  }
  gate_mfma_kernel<<<TT / 128, 256, 0, stream>>>(x, Wg, bg, xb, gate_e, gate_w,
                                                 counts, nretry, retry);
  gatefix_kernel<<<RETRYCAP / 16, 256, 0, stream>>>(x, Wg, bg, nretry, retry,
                                                    gate_e, gate_w, counts);
  route_kernel<<<1, 256, 0, stream>>>(gate_e, gate_w, counts, tile_expert,
                                      ntiles, slot_token, slot_w, slot_of);
  {
    dim3 g(HH / 128, MAXTILES);
    gemm1_kernel<<<g, 256, 0, stream>>>(xb, w1t, b1, slot_token, tile_expert, ntiles, hb);
  }
  {
    dim3 g(DD / 128, MAXTILES);
    if (use_y)
      gemm2_kernel<1><<<g, 256, 0, stream>>>(hb, w2t, b2, slot_token, slot_w,
                                             tile_expert, ntiles, yw, out);
    else
      gemm2_kernel<0><<<g, 256, 0, stream>>>(hb, w2t, b2, slot_token, slot_w,
                                             tile_expert, ntiles, yw, out);
  }
  if (use_y) {
    combine_kernel<<<TT * (DD / 8) / 256, 256, 0, stream>>>(yw, slot_of, out);
  }
}